// Round 18
// baseline (141.055 us; speedup 1.0000x reference)
//
#include <hip/hip_runtime.h>
#include <math.h>

// -----------------------------------------------------------------------------
// Round 18: STREAM-UNMIX experiment. Five structures all pin at ~2.4 TB/s
// HBM-side with 2R+1W interleaved -> split into two pass-pure kernels:
//   Pass A (read-pure): r16's LDS gather+reduce, writes a 16B record/feature
//           {uhot, t1u, t2u, h<<8|t1i} to d_ws. No transcendentals, no traj.
//   Pass B (write-pure): coalesced 16B record loads (lane=feature), 2 exact
//           cr_g, r17's in-wave fixup (u re-read from global for the rare
//           flagged features), r16's shfl-patched coalesced output stores.
// Fallback (ws_size too small for 16MB records): r17-minus-NT single kernel.
// d_ws: [0..64] traj floats; records at byte offset 512.
// -----------------------------------------------------------------------------

__device__ __forceinline__ float cr_logf32(float x) { return (float)log((double)x); }

__device__ __forceinline__ float cr_g(float u) {
    float c0 = __fadd_rn(u, 1e-30f);
    float t2 = cr_logf32(c0);
    float t3 = __fadd_rn(-t2, 1e-30f);
    float t4 = cr_logf32(t3);
    return -t4;
}

__global__ void traj_kernel(const float* __restrict__ log_x0,
                            const int* __restrict__ t_ptr,
                            float* __restrict__ traj) {
    __shared__ float ac[1001];
    __shared__ float sig[1000];
    __shared__ float init2[2];
    int t = *t_ptr;
    if (t > 1000) t = 1000;
    if (t < 0) t = 0;

    for (int s = threadIdx.x; s <= t; s += blockDim.x) {
        float a = __fdiv_rn((float)s, 1000.0f);
        float b = __fadd_rn(a, 0.008f);
        float c = __fdiv_rn(b, 1.008f);
        float d = __fmul_rn(c, 0x1.921fb6p+1f);  // fl32(pi)
        float e = __fmul_rn(d, 0.5f);
        float cs = (float)cos((double)e);        // CR f32 cos
        ac[s] = __fmul_rn(cs, cs);
    }
    if (threadIdx.x == 0) {
        float hotf = -1e30f, coldf = 1e30f;
        for (int j = 0; j < 32; ++j) {
            float v = log_x0[j];
            hotf = fmaxf(hotf, v);
            coldf = fminf(coldf, v);
        }
        init2[0] = hotf;
        init2[1] = coldf;
        traj[64] = coldf;
    }
    __syncthreads();
    for (int s = threadIdx.x + 1; s <= t; s += blockDim.x)
        sig[s - 1] = __fsub_rn(1.0f, __fdiv_rn(ac[s], ac[s - 1]));
    __syncthreads();

    if (threadIdx.x < 32) {
        const int h = threadIdx.x;   // hot-bin position (einsum f32 sum order)
        float lh = init2[0];
        float lc = init2[1];
        for (int k = 0; k < t; ++k) {
            float sg = sig[k];
            float ph = (float)exp((double)lh);
            float pc = (float)exp((double)lc);
            float th = __fmul_rn(ph, 0.03125f);
            float tc = __fmul_rn(pc, 0.03125f);
            float acc = 0.0f;
            for (int i = 0; i < 32; ++i)
                acc = __fadd_rn(acc, (i == h) ? th : tc);
            float s1  = __fsub_rn(1.0f, sg);
            float sm  = __fmul_rn(sg, acc);
            float phn = __fadd_rn(__fmul_rn(s1, ph), sm);
            float pcn = __fadd_rn(__fmul_rn(s1, pc), sm);
            lh = cr_logf32(__fadd_rn(phn, 1e-8f));
            lc = cr_logf32(__fadd_rn(pcn, 1e-8f));
        }
        traj[h]      = lh;
        traj[32 + h] = lc;
    }
}

// branchless scan step: mask hot bin, track top-2 value + first-visited index
#define SCANB(VAL, IDX)                                         \
    {                                                           \
        const float cu = ((IDX) == hc) ? -1.0f : (VAL);         \
        const bool gt1 = cu > t1u;                              \
        const bool gt2 = cu > t2u;                              \
        t2u = gt1 ? t1u : (gt2 ? cu : t2u);                     \
        t1i = gt1 ? (IDX) : t1i;                                \
        t1u = gt1 ? cu : t1u;                                   \
    }

// ---------- gather + reduce common body: fills hc,h,t1u,t2u,t1i,uhot --------
#define GATHER_REDUCE_BODY                                                     \
    float4 xr[8];                                                              \
    _Pragma("unroll")                                                          \
    for (int k = 0; k < 8; ++k) xr[k] = log_x0[fb4 + k * 64 + lane];           \
    float4 ur[8];                                                              \
    _Pragma("unroll")                                                          \
    for (int k = 0; k < 8; ++k) ur[k] = u[fb4 + k * 64 + lane];                \
    const int sgb = lane & ~7;                                                 \
    _Pragma("unroll")                                                          \
    for (int k = 0; k < 8; ++k) {                                              \
        const float4 xv = xr[k];                                               \
        int p = -1;                                                            \
        p = (xv.x > -1.0f) ? 0 : p;                                            \
        p = (xv.y > -1.0f) ? 1 : p;                                            \
        p = (xv.z > -1.0f) ? 2 : p;                                            \
        p = (xv.w > -1.0f) ? 3 : p;                                            \
        const unsigned long long bal = __ballot(p >= 0);                       \
        const unsigned mm = (unsigned)((bal >> sgb) & 0xFFull);                \
        const int hlane = (int)__ffs(mm) - 1;                                  \
        const int psrc  = __shfl(p, sgb + ((hlane < 0) ? 0 : hlane), 64);      \
        const int hbin  = (hlane < 0) ? 255 : (hlane * 4 + psrc);              \
        if ((lane & 7) == 0)                                                   \
            lds_h[w][k * 8 + (lane >> 3)] = (unsigned char)hbin;               \
    }                                                                          \
    _Pragma("unroll")                                                          \
    for (int k = 0; k < 8; ++k)                                                \
        *(float4*)&lds_u[w][k * 256 + lane * 4] = ur[k];                       \
    __syncthreads();                                                           \
    const int   h  = (int)lds_h[w][lane];                                      \
    const int   hc = (h > 31) ? 0 : h;                                         \
    const float4* urow4 = (const float4*)&lds_u[w][lane * 32];                 \
    float t1u = -1.0f, t2u = -1.0f; int t1i = 0;                               \
    _Pragma("unroll")                                                          \
    for (int q = 0; q < 8; ++q) {                                              \
        const int qq = (q + lane) & 7;                                         \
        const float4 v = urow4[qq];                                            \
        const int b0 = qq * 4;                                                 \
        SCANB(v.x, b0) SCANB(v.y, b0 + 1) SCANB(v.z, b0 + 2) SCANB(v.w, b0+3) \
    }                                                                          \
    const float uhot = lds_u[w][lane * 32 + hc];

// ---------------- Pass A: read-pure, write 16B record per feature -----------
__global__ void passA_kernel(const float4* __restrict__ log_x0,
                             const float4* __restrict__ u,
                             float4* __restrict__ rec) {
    __shared__ float lds_u[4][2048];
    __shared__ unsigned char lds_h[4][64];

    const int w    = threadIdx.x >> 6;
    const int lane = threadIdx.x & 63;
    const int tile = (int)((blockIdx.x * blockDim.x + threadIdx.x) >> 6);
    const size_t fb4 = (size_t)tile * 512;

    GATHER_REDUCE_BODY

    float4 r;
    r.x = uhot;
    r.y = t1u;
    r.z = t2u;
    r.w = __uint_as_float((unsigned)((h << 8) | t1i));
    rec[(size_t)tile * 64 + lane] = r;           // 16B coalesced
}

// ---------------- Pass B: write-pure, records -> output ----------------------
__global__ void passB_kernel(const float4* __restrict__ rec,
                             const float* __restrict__ uflat,
                             const float* __restrict__ trajm,
                             float4* __restrict__ out,
                             int ntile) {
    __shared__ float lh_s[32], lc_s[32];
    __shared__ float coldv_s;
    if (threadIdx.x < 32) {
        lh_s[threadIdx.x] = trajm[threadIdx.x];
        lc_s[threadIdx.x] = trajm[32 + threadIdx.x];
    }
    if (threadIdx.x == 0) coldv_s = trajm[64];
    __syncthreads();
    const float coldv = coldv_s;

    const int lane = threadIdx.x & 63;
    const int wid  = (int)((blockIdx.x * blockDim.x + threadIdx.x) >> 6);
    const int nwav = (int)((gridDim.x * blockDim.x) >> 6);

    for (int tile = wid; tile < ntile; tile += nwav) {
        const float4 r = rec[(size_t)tile * 64 + lane];      // 16B coalesced
        const float uhot = r.x, t1u = r.y, t2u = r.z;
        const unsigned pk = __float_as_uint(r.w);
        const int h   = (int)(pk >> 8);
        const int t1i = (int)(pk & 255u);
        const int hc  = (h > 31) ? 0 : h;
        const float lh = lh_s[hc];
        const float lc = lc_s[hc];

        const float s_hot  = __fadd_rn(lh, cr_g(uhot));
        const float s_cold = __fadd_rn(lc, cr_g(t1u));
        int widx;
        if (s_hot > s_cold)      widx = hc;
        else if (s_hot < s_cold) widx = t1i;
        else                     widx = (hc < t1i) ? hc : t1i;

        // in-wave exact fixup (r17-proven loop shape; u read from global)
        const bool flagged = ((t1u - t2u) < 1e-6f) | (h > 31);
        unsigned long long fm = __ballot(flagged);
        while (fm) {
            const int fl = (int)__builtin_ctzll(fm);
            fm &= fm - 1;
            const int fh  = __shfl(h, (lane & ~63) + fl, 64);
            const int fhc = (fh > 31) ? 0 : fh;
            const int l32 = lane & 31;
            const size_t fbase = ((size_t)tile * 64 + fl) * 32;
            const float uj  = uflat[fbase + l32];
            const bool jhot = (l32 == fhc) && (fh <= 31);
            float s = __fadd_rn(jhot ? lh_s[fhc] : lc_s[fhc], cr_g(uj));
            int idx = l32;
            #pragma unroll
            for (int m = 16; m > 0; m >>= 1) {
                float os = __shfl_xor(s,   m, 32);
                int   oi = __shfl_xor(idx, m, 32);
                if (os > s || (os == s && oi < idx)) { s = os; idx = oi; }
            }
            if (lane == fl) widx = idx;
        }

        const size_t fb4 = (size_t)tile * 512;
        #pragma unroll
        for (int k = 0; k < 8; ++k) {
            const int src = k * 8 + (lane >> 3);
            const int wk  = __shfl(widx, src, 64);
            const int qb  = (lane & 7) * 4;
            float4 o;
            o.x = (wk == qb    ) ? 0.0f : coldv;
            o.y = (wk == qb + 1) ? 0.0f : coldv;
            o.z = (wk == qb + 2) ? 0.0f : coldv;
            o.w = (wk == qb + 3) ? 0.0f : coldv;
            out[fb4 + k * 64 + lane] = o;
        }
    }
}

// ------------- Fallback: r17 single kernel, regular stores ------------------
__global__ void fused_kernel(const float4* __restrict__ log_x0,
                             const float4* __restrict__ u,
                             const float* __restrict__ trajm,
                             float4* __restrict__ out) {
    __shared__ float lds_u[4][2048];
    __shared__ unsigned char lds_h[4][64];
    __shared__ float lh_s[32], lc_s[32];
    __shared__ float coldv_s;
    if (threadIdx.x < 32) {
        lh_s[threadIdx.x] = trajm[threadIdx.x];
        lc_s[threadIdx.x] = trajm[32 + threadIdx.x];
    }
    if (threadIdx.x == 0) coldv_s = trajm[64];

    const int w    = threadIdx.x >> 6;
    const int lane = threadIdx.x & 63;
    const int tile = (int)((blockIdx.x * blockDim.x + threadIdx.x) >> 6);
    const size_t fb4 = (size_t)tile * 512;

    GATHER_REDUCE_BODY

    const float lh = lh_s[hc];
    const float lc = lc_s[hc];
    const float coldv = coldv_s;

    const float s_hot  = __fadd_rn(lh, cr_g(uhot));
    const float s_cold = __fadd_rn(lc, cr_g(t1u));
    int widx;
    if (s_hot > s_cold)      widx = hc;
    else if (s_hot < s_cold) widx = t1i;
    else                     widx = (hc < t1i) ? hc : t1i;

    const bool flagged = ((t1u - t2u) < 1e-6f) | (h > 31);
    unsigned long long fm = __ballot(flagged);
    while (fm) {
        const int fl = (int)__builtin_ctzll(fm);
        fm &= fm - 1;
        const int fh  = (int)lds_h[w][fl];
        const int fhc = (fh > 31) ? 0 : fh;
        const int l32 = lane & 31;
        const float uj  = lds_u[w][fl * 32 + l32];
        const bool jhot = (l32 == fhc) && (fh <= 31);
        float s = __fadd_rn(jhot ? lh_s[fhc] : lc_s[fhc], cr_g(uj));
        int idx = l32;
        #pragma unroll
        for (int m = 16; m > 0; m >>= 1) {
            float os = __shfl_xor(s,   m, 32);
            int   oi = __shfl_xor(idx, m, 32);
            if (os > s || (os == s && oi < idx)) { s = os; idx = oi; }
        }
        if (lane == fl) widx = idx;
    }

    #pragma unroll
    for (int k = 0; k < 8; ++k) {
        const int src = k * 8 + (lane >> 3);
        const int wk  = __shfl(widx, src, 64);
        const int qb  = (lane & 7) * 4;
        float4 o;
        o.x = (wk == qb    ) ? 0.0f : coldv;
        o.y = (wk == qb + 1) ? 0.0f : coldv;
        o.z = (wk == qb + 2) ? 0.0f : coldv;
        o.w = (wk == qb + 3) ? 0.0f : coldv;
        out[fb4 + k * 64 + lane] = o;
    }
}

extern "C" void kernel_launch(void* const* d_in, const int* in_sizes, int n_in,
                              void* d_out, int out_size, void* d_ws, size_t ws_size,
                              hipStream_t stream) {
    const float* log_x0 = (const float*)d_in[0];
    const float* u      = (const float*)d_in[1];
    const int*   t_ptr  = (const int*)d_in[2];
    float* out  = (float*)d_out;
    float* traj = (float*)d_ws;

    const int nfeat = in_sizes[0] / 32;   // B*F = 1,048,576
    const int ntile = nfeat / 64;         // 16384 tiles
    const int nblk  = ntile / 4;          // 4 waves/block, 1 tile/wave

    const size_t rec_off   = 512;                       // bytes
    const size_t rec_bytes = (size_t)nfeat * 16;

    traj_kernel<<<1, 128, 0, stream>>>(log_x0, t_ptr, traj);

    if (ws_size >= rec_off + rec_bytes) {
        float4* rec = (float4*)((char*)d_ws + rec_off);
        passA_kernel<<<nblk, 256, 0, stream>>>((const float4*)log_x0,
                                               (const float4*)u, rec);
        passB_kernel<<<2048, 256, 0, stream>>>(rec, u, traj,
                                               (float4*)out, ntile);
    } else {
        fused_kernel<<<nblk, 256, 0, stream>>>((const float4*)log_x0,
                                               (const float4*)u, traj,
                                               (float4*)out);
    }
}